// Round 5
// baseline (108.185 us; speedup 1.0000x reference)
//
#include <hip/hip_runtime.h>

#define BLK 64
#define STRIDE 79          // words per thread LDS region (odd => conflict-free)
#define NCC 64
#define NFF 16
#define NZ  80

__device__ __forceinline__ float fast_rcp(float x) { return __builtin_amdgcn_rcpf(x); }

// in-place inclusive prefix product, chunked-scan (serial-8 + KS over totals)
template<int N>
__device__ __forceinline__ void prefix_mul(float* x) {
#pragma unroll
    for (int c = 0; c < N; c += 8) {
#pragma unroll
        for (int i = 1; i < 8; i++)
            if (c + i < N) x[c + i] *= x[c + i - 1];
    }
    constexpr int G = (N + 7) / 8;
    float t[G];
#pragma unroll
    for (int g = 0; g < G; g++) {
        int e = 8 * g + 7; if (e > N - 1) e = N - 1;
        t[g] = x[e];
    }
#pragma unroll
    for (int sh = 1; sh < G; sh <<= 1) {
#pragma unroll
        for (int g = G - 1; g >= sh; --g) t[g] *= t[g - sh];
    }
#pragma unroll
    for (int g = 1; g < G; g++) {
#pragma unroll
        for (int i = 0; i < 8; i++)
            if (8 * g + i < N) x[8 * g + i] *= t[g - 1];
    }
}

template<int N>
__device__ __forceinline__ void prefix_add(float* x) {
#pragma unroll
    for (int c = 0; c < N; c += 8) {
#pragma unroll
        for (int i = 1; i < 8; i++)
            if (c + i < N) x[c + i] += x[c + i - 1];
    }
    constexpr int G = (N + 7) / 8;
    float t[G];
#pragma unroll
    for (int g = 0; g < G; g++) {
        int e = 8 * g + 7; if (e > N - 1) e = N - 1;
        t[g] = x[e];
    }
#pragma unroll
    for (int sh = 1; sh < G; sh <<= 1) {
#pragma unroll
        for (int g = G - 1; g >= sh; --g) t[g] += t[g - sh];
    }
#pragma unroll
    for (int g = 1; g < G; g++) {
#pragma unroll
        for (int i = 0; i < 8; i++)
            if (8 * g + i < N) x[8 * g + i] += t[g - 1];
    }
}

__global__ void __launch_bounds__(BLK, 2)
VolumeRenderer_16192026706363_kernel(const float* __restrict__ ros,
                                     const float* __restrict__ rds,
                                     const float* __restrict__ w_sigma,
                                     const float* __restrict__ w_feat,
                                     const float* __restrict__ u,
                                     float* __restrict__ out,
                                     int nrays)
{
    __shared__ float lds[BLK * STRIDE];     // 20,224 B -> 8 blocks/CU
    const int tid = threadIdx.x;
    const int n = blockIdx.x * BLK + tid;
    float* my = &lds[tid * STRIDE];

    const float LOG2E = 1.4426950408889634f;
    const float NEGL2E = -LOG2E;
    const float DIST = 4.0f / 63.0f;
    const float K1 = -DIST * LOG2E;

    // --- issue independent loads early --------------------------------------
    const float4* u4p = reinterpret_cast<const float4*>(u + (size_t)n * 16);
    float4 uq0 = u4p[0], uq1 = u4p[1], uq2 = u4p[2], uq3 = u4p[3];
    const float ro0 = ros[n * 3 + 0], ro1 = ros[n * 3 + 1], ro2 = ros[n * 3 + 2];
    const float rd0 = rds[n * 3 + 0], rd1 = rds[n * 3 + 1], rd2 = rds[n * 3 + 2];
    const float s0 = w_sigma[0], s1 = w_sigma[1], s2 = w_sigma[2];

    // affine field:  sigma(z) = sgA + sgB z ;  logit_c(z) = fA[c] + fB[c] z
    const float sgA = ro0 * s0 + ro1 * s1 + ro2 * s2;
    const float sgB = rd0 * s0 + rd1 * s1 + rd2 * s2;
    float fA[3], fB[3];
#pragma unroll
    for (int c = 0; c < 3; c++) {
        fA[c] = ro0 * w_feat[0 * 3 + c] + ro1 * w_feat[1 * 3 + c] + ro2 * w_feat[2 * 3 + c];
        fB[c] = rd0 * w_feat[0 * 3 + c] + rd1 * w_feat[1 * 3 + c] + rd2 * w_feat[2 * 3 + c];
    }

    // --- coarse pass: all factors independent, then prefix trees ------------
    // g[i] = e_i + 1e-10 ; after prefix_mul g[i] = T_i = prod_{j<=i}(e_j+1e-10)
    // w_i = (1-e_i) T_{i-1} = T_{i-1} - T_i + O(1e-10)
    float g[63];
#pragma unroll
    for (int i = 0; i < 63; i++) {
        float zc = 2.0f + DIST * (float)i;          // compile-time constant
        float sg = fmaf(sgB, zc, sgA);
        g[i] = exp2f(fmaxf(sg, 0.0f) * K1) + 1e-10f;
    }
    prefix_mul<63>(g);

    float c[63];
    c[0] = 0.0f;
#pragma unroll
    for (int i = 1; i <= 62; i++) c[i] = (g[i - 1] - g[i]) + 1e-5f;
    prefix_add<62>(c + 1);

    my[0] = 0.0f;
#pragma unroll
    for (int i = 1; i <= 62; i++) my[i] = c[i];     // unnormalized cdf -> LDS
    const float S = c[62];
    const float invS = fast_rcp(S);

    // --- 16 binary searches (ILP across q, 6 dependent LDS levels) ----------
    float uarr[16];
    uarr[0]=uq0.x; uarr[1]=uq0.y; uarr[2]=uq0.z; uarr[3]=uq0.w;
    uarr[4]=uq1.x; uarr[5]=uq1.y; uarr[6]=uq1.z; uarr[7]=uq1.w;
    uarr[8]=uq2.x; uarr[9]=uq2.y; uarr[10]=uq2.z; uarr[11]=uq2.w;
    uarr[12]=uq3.x; uarr[13]=uq3.y; uarr[14]=uq3.z; uarr[15]=uq3.w;

    float tv[16];
#pragma unroll
    for (int q = 0; q < 16; q++) {
        float uu = uarr[q];
        float us = uu * S;
        int lo = 0, hi = 63;
#pragma unroll
        for (int s = 0; s < 6; s++) {
            int mid = (lo + hi) >> 1;
            bool lt = (my[mid] < us);
            lo = lt ? mid + 1 : lo;
            hi = lt ? hi : mid;
        }
        int ind = lo;
        int below = (ind - 1 > 0) ? ind - 1 : 0;
        int above = (ind < 62) ? ind : 62;
        float c0 = my[below] * invS, c1 = my[above] * invS;
        float b0 = fmaf(DIST, (float)below, 2.0f + 0.5f * DIST);   // tm(below)
        float denom = c1 - c0;
        denom = (denom < 1e-5f) ? 1.0f : denom;
        float db = (above > below) ? DIST : 0.0f;
        tv[q] = fmaf((uu - c0) * fast_rcp(denom), db, b0);
    }

    // --- bitonic sort of 16 fine samples (registers) ------------------------
#pragma unroll
    for (int k = 2; k <= 16; k <<= 1) {
#pragma unroll
        for (int j = k >> 1; j > 0; j >>= 1) {
#pragma unroll
            for (int i = 0; i < 16; i++) {
                int l = i ^ j;
                if (l > i) {
                    float a = tv[i], b = tv[l];
                    float mn = fminf(a, b), mx = fmaxf(a, b);
                    bool up = ((i & k) == 0);
                    tv[i] = up ? mn : mx;
                    tv[l] = up ? mx : mn;
                }
            }
        }
    }

    // --- rank-scatter fine samples into merge slots -------------------------
    // merged position of fine j: m_j = j + (#coarse <= t_j), coarse wins ties.
    // #coarse <= t = floor((t-2)*63/4)+1 in [1,63]  =>  m in [1,78];
    // slots 0 and 79 are always coarse, so store slot m-1 in a 78-slot array.
#pragma unroll
    for (int k = 0; k < 78; k++) my[k] = -1.0f;     // sentinel
#pragma unroll
    for (int j = 0; j < 16; j++) {
        float x = (tv[j] - 2.0f) * 15.75f;          // *63/4
        int L = (int)floorf(x) + 1;
        L = (L < 1) ? 1 : (L > 63 ? 63 : L);
        my[j + L - 1] = tv[j];
    }

    // --- reconstruct merged z[0..79] (only cnt-chain is serial) -------------
    float z[NZ];
    z[0] = 2.0f;
    z[NZ - 1] = 6.0f;
    {
        float fc = 0.0f;                            // fine seen so far
#pragma unroll
        for (int k = 1; k <= 78; k++) {
            float s = my[k - 1];
            bool fine = (s >= 0.0f);
            float zc = fmaf(DIST, (float)k - fc, 2.0f);
            z[k] = fine ? s : zc;
            fc += fine ? 1.0f : 0.0f;
        }
    }

    // --- transmittance factors (independent) + prefix product ---------------
    float pp[NZ];
    float dl = 0.0f;
#pragma unroll
    for (int k = 0; k < NZ; k++) {
        float d;
        if (k < NZ - 1) { d = z[k + 1] - z[k]; dl = d; }
        else d = dl;                                 // last dist repeats
        float sg = fmaf(sgB, z[k], sgA);
        pp[k] = exp2f(fmaxf(sg, 0.0f) * (d * NEGL2E)) + 1e-10f;
    }
    prefix_mul<NZ>(pp);                              // pp[k] = T_k

    // --- weights, features, accumulation, streamed float4 writes ------------
    float a0 = 0.f, a1 = 0.f, a2 = 0.f, ad = 0.f;
    float b0a = 0.f, b1a = 0.f, b2a = 0.f, bda = 0.f;
    float* wptr = out + (size_t)nrays * 4 + (size_t)n * NZ;
#pragma unroll
    for (int gq = 0; gq < 20; gq++) {
        float wq[4];
#pragma unroll
        for (int j = 0; j < 4; j++) {
            int k = 4 * gq + j;
            float prev = (k == 0) ? 1.0f : pp[k - 1];
            float w = prev - pp[k];                  // = alpha_k * T_{k-1}
            float zk = z[k];
            float e0 = exp2f(fmaf(fB[0], zk, fA[0]) * NEGL2E);
            float e1 = exp2f(fmaf(fB[1], zk, fA[1]) * NEGL2E);
            float e2 = exp2f(fmaf(fB[2], zk, fA[2]) * NEGL2E);
            float f0 = fast_rcp(1.0f + e0);
            float f1 = fast_rcp(1.0f + e1);
            float f2 = fast_rcp(1.0f + e2);
            if (j & 1) {
                b0a = fmaf(w, f0, b0a); b1a = fmaf(w, f1, b1a);
                b2a = fmaf(w, f2, b2a); bda = fmaf(w, zk, bda);
            } else {
                a0 = fmaf(w, f0, a0); a1 = fmaf(w, f1, a1);
                a2 = fmaf(w, f2, a2); ad = fmaf(w, zk, ad);
            }
            wq[j] = w;
        }
        *reinterpret_cast<float4*>(wptr + 4 * gq) =
            make_float4(wq[0], wq[1], wq[2], wq[3]);
    }

    out[(size_t)n * 3 + 0] = a0 + b0a;
    out[(size_t)n * 3 + 1] = a1 + b1a;
    out[(size_t)n * 3 + 2] = a2 + b2a;
    out[(size_t)nrays * 3 + n] = ad + bda;
}

extern "C" void kernel_launch(void* const* d_in, const int* in_sizes, int n_in,
                              void* d_out, int out_size, void* d_ws, size_t ws_size,
                              hipStream_t stream) {
    const float* ros = (const float*)d_in[0];
    const float* rds = (const float*)d_in[1];
    const float* w_sigma = (const float*)d_in[2];
    const float* w_feat = (const float*)d_in[3];
    const float* u = (const float*)d_in[4];
    float* out = (float*)d_out;

    int nrays = in_sizes[0] / 3;          // 131072
    int grid = nrays / BLK;               // 2048
    VolumeRenderer_16192026706363_kernel<<<grid, BLK, 0, stream>>>(
        ros, rds, w_sigma, w_feat, u, out, nrays);
}

// Round 6
// 102.016 us; speedup vs baseline: 1.0605x; 1.0605x over previous
//
#include <hip/hip_runtime.h>

#define BLK 128            // 4 lanes per ray -> 32 rays/block
#define RPB 32
#define STRIDE 79          // odd -> conflict-friendly
#define NZ  80

__device__ __forceinline__ float fast_rcp(float x) { return __builtin_amdgcn_rcpf(x); }

// 4-lane group helpers (absolute-lane shuffles, width 64 default)
__device__ __forceinline__ void grp_gather4(float v, int gb, float o[4]) {
    o[0] = __shfl(v, gb + 0); o[1] = __shfl(v, gb + 1);
    o[2] = __shfl(v, gb + 2); o[3] = __shfl(v, gb + 3);
}

__global__ void __launch_bounds__(BLK, 4)
VolumeRenderer_16192026706363_kernel(const float* __restrict__ ros,
                                     const float* __restrict__ rds,
                                     const float* __restrict__ w_sigma,
                                     const float* __restrict__ w_feat,
                                     const float* __restrict__ u,
                                     float* __restrict__ out,
                                     int nrays)
{
    __shared__ float lds[RPB * STRIDE];       // 10,112 B
    const int tid  = threadIdx.x;
    const int gl   = tid & 3;                 // lane within 4-lane ray group
    const int rloc = tid >> 2;                // ray within block
    const int ray  = blockIdx.x * RPB + rloc;
    const int wl   = tid & 63;                // lane within wave
    const int gb   = wl & ~3;                 // group base (absolute wave lane)
    float* my = &lds[rloc * STRIDE];

    const float LOG2E  = 1.4426950408889634f;
    const float NEGL2E = -LOG2E;
    const float DIST   = 4.0f / 63.0f;
    const float K1     = -DIST * LOG2E;

    // --- early loads ---------------------------------------------------------
    const float4 uq = *reinterpret_cast<const float4*>(u + (size_t)ray * 16 + gl * 4);
    const float ro0 = ros[ray * 3 + 0], ro1 = ros[ray * 3 + 1], ro2 = ros[ray * 3 + 2];
    const float rd0 = rds[ray * 3 + 0], rd1 = rds[ray * 3 + 1], rd2 = rds[ray * 3 + 2];
    const float s0 = w_sigma[0], s1 = w_sigma[1], s2 = w_sigma[2];

    const float sgA = ro0 * s0 + ro1 * s1 + ro2 * s2;
    const float sgB = rd0 * s0 + rd1 * s1 + rd2 * s2;
    float fA[3], fB[3];
#pragma unroll
    for (int c = 0; c < 3; c++) {
        fA[c] = ro0 * w_feat[0 * 3 + c] + ro1 * w_feat[1 * 3 + c] + ro2 * w_feat[2 * 3 + c];
        fB[c] = rd0 * w_feat[0 * 3 + c] + rd1 * w_feat[1 * 3 + c] + rd2 * w_feat[2 * 3 + c];
    }

    // --- phase A: coarse transmittance + cdf (16 samples/lane) ---------------
    // lane gl handles i in [16*gl, 16*gl+16) of coarse indices 0..63 (i=63 dummy)
    const int base = gl * 16;
    float pl[16];
    {
        float p = 1.0f;
#pragma unroll
        for (int t = 0; t < 16; t++) {
            float zc = fmaf(DIST, (float)(base + t), 2.0f);
            float e = exp2f(fmaxf(fmaf(sgB, zc, sgA), 0.0f) * K1) + 1e-10f;
            p *= e; pl[t] = p;
        }
    }
    float Ltot = (gl == 3) ? pl[14] : pl[15];       // exclude dummy i=63
    float x4[4];
    grp_gather4(Ltot, gb, x4);
    const float Eprod = (gl == 0) ? 1.0f : (gl == 1) ? x4[0]
                      : (gl == 2) ? x4[0] * x4[1] : x4[0] * x4[1] * x4[2];

    // lane-local cdf contributions (i in 1..62 only)
    float Lsum;
    {
        float cs = 0.0f;
#pragma unroll
        for (int t = 0; t < 16; t++) {
            int i = base + t;
            float plprev = (t == 0) ? 1.0f : pl[t - 1];
            float w = Eprod * (plprev - pl[t]);     // T_{i-1} - T_i
            if (i >= 1 && i <= 62) cs += w + 1e-5f;
        }
        Lsum = cs;
    }
    grp_gather4(Lsum, gb, x4);
    const float Csum0 = (gl == 0) ? 0.0f : (gl == 1) ? x4[0]
                      : (gl == 2) ? x4[0] + x4[1] : x4[0] + x4[1] + x4[2];
    const float S = x4[0] + x4[1] + x4[2] + x4[3];
    const float invS = fast_rcp(S);

    // write cdf slots
    {
        float cs = 0.0f;
#pragma unroll
        for (int t = 0; t < 16; t++) {
            int i = base + t;
            float plprev = (t == 0) ? 1.0f : pl[t - 1];
            float w = Eprod * (plprev - pl[t]);
            if (i >= 1 && i <= 62) { cs += w + 1e-5f; my[i] = Csum0 + cs; }
        }
        if (gl == 0) my[0] = 0.0f;
    }

    // --- phase B: 4 binary searches per lane ---------------------------------
    float tv[4];
#pragma unroll
    for (int q = 0; q < 4; q++) {
        float uu = (q == 0) ? uq.x : (q == 1) ? uq.y : (q == 2) ? uq.z : uq.w;
        float us = uu * S;
        int lo = 0, hi = 63;
#pragma unroll
        for (int s = 0; s < 6; s++) {
            int mid = (lo + hi) >> 1;
            bool lt = (my[mid] < us);
            lo = lt ? mid + 1 : lo;
            hi = lt ? hi : mid;
        }
        int ind = lo;
        int below = (ind - 1 > 0) ? ind - 1 : 0;
        int above = (ind < 62) ? ind : 62;
        float c0 = my[below] * invS, c1 = my[above] * invS;
        float b0 = fmaf(DIST, (float)below, 2.0f + 0.5f * DIST);
        float denom = c1 - c0;
        denom = (denom < 1e-5f) ? 1.0f : denom;
        float db = (above > below) ? DIST : 0.0f;
        tv[q] = fmaf((uu - c0) * fast_rcp(denom), db, b0);
    }

    // --- phase C: gather all 16 into each lane, redundant bitonic sort -------
    float arr[16];
#pragma unroll
    for (int k = 0; k < 4; k++) {
        float g4[4];
        grp_gather4(tv[k], gb, g4);
#pragma unroll
        for (int s = 0; s < 4; s++) arr[s * 4 + k] = g4[s];
    }
#pragma unroll
    for (int k = 2; k <= 16; k <<= 1) {
#pragma unroll
        for (int j = k >> 1; j > 0; j >>= 1) {
#pragma unroll
            for (int i = 0; i < 16; i++) {
                int l = i ^ j;
                if (l > i) {
                    float a = arr[i], b = arr[l];
                    float mn = fminf(a, b), mx = fmaxf(a, b);
                    bool up = ((i & k) == 0);
                    arr[i] = up ? mn : mx;
                    arr[l] = up ? mx : mn;
                }
            }
        }
    }

    // --- phase D: sentinel init + disjoint rank-scatter ----------------------
#pragma unroll
    for (int t = 0; t < 20; t++) {
        int j = gl + 4 * t;
        if (j < 78) my[j] = -1.0f;
    }
#pragma unroll
    for (int q = 0; q < 4; q++) {
        int j = gl * 4 + q;                       // sorted index owned by lane
        float v = arr[j];
        float x = (v - 2.0f) * 15.75f;            // *63/4
        int L = (int)floorf(x) + 1;
        L = (L < 1) ? 1 : (L > 63 ? 63 : L);
        my[j + L - 1] = v;                        // merged slot m-1, disjoint
    }

    // --- phase E: reconstruct merged z (20 positions per lane) ---------------
    // lane gl owns slots [20gl, 20gl+slen), slen = 20,20,20,18
    const int sbase = 20 * gl;
    const int slen = (gl < 3) ? 20 : 18;
    float sv[20], fl[20];
    float lt = 0.0f;
#pragma unroll
    for (int t = 0; t < 20; t++) {
        if (t < slen) {
            sv[t] = my[sbase + t];
            fl[t] = (sv[t] >= 0.0f) ? 1.0f : 0.0f;
            lt += fl[t];
        } else { sv[t] = 0.0f; fl[t] = 0.0f; }
    }
    grp_gather4(lt, gb, x4);
    float fcnt = (gl == 0) ? 0.0f : (gl == 1) ? x4[0]
               : (gl == 2) ? x4[0] + x4[1] : x4[0] + x4[1] + x4[2];

    float zpos[20];                               // z at positions sbase+1..sbase+slen
#pragma unroll
    for (int t = 0; t < 20; t++) {
        if (t < slen) {
            float zc = fmaf(DIST, (float)(sbase + t + 1) - fcnt, 2.0f);
            zpos[t] = (fl[t] > 0.0f) ? sv[t] : zc;
            fcnt += fl[t];
        } else zpos[t] = 0.0f;
    }
    // carry: z[20gl] comes from lane gl-1's zpos[19] (lane0 -> 2.0)
    int src = gb + ((gl == 0) ? 0 : gl - 1);
    float carry = __shfl(zpos[19], src);
    float myz[20];
    myz[0] = (gl == 0) ? 2.0f : carry;
#pragma unroll
    for (int t = 1; t < 20; t++) {
        int idx = t - 1;
        myz[t] = (idx < slen) ? zpos[idx] : 6.0f; // lane3 t=19 -> z[79]=6
    }

    // --- phase F: transmittance factors + 4-lane product scan ----------------
    float d[20];
#pragma unroll
    for (int t = 0; t < 19; t++) d[t] = myz[t + 1] - myz[t];
    d[19] = (gl < 3) ? (zpos[19] - myz[19]) : d[18];  // pos79 repeats last dist

    float Pl[20];
    {
        float p = 1.0f;
#pragma unroll
        for (int t = 0; t < 20; t++) {
            float sg = fmaf(sgB, myz[t], sgA);
            float e = exp2f(fmaxf(sg, 0.0f) * (d[t] * NEGL2E)) + 1e-10f;
            p *= e; Pl[t] = p;
        }
    }
    grp_gather4(Pl[19], gb, x4);
    const float E2 = (gl == 0) ? 1.0f : (gl == 1) ? x4[0]
                   : (gl == 2) ? x4[0] * x4[1] : x4[0] * x4[1] * x4[2];

    // --- phase G: weights, features, accumulate, write -----------------------
    float a0 = 0.f, a1 = 0.f, a2 = 0.f, ad = 0.f;
    float* wptr = out + (size_t)nrays * 4 + (size_t)ray * NZ + sbase;
#pragma unroll
    for (int g5 = 0; g5 < 5; g5++) {
        float wq[4];
#pragma unroll
        for (int j = 0; j < 4; j++) {
            int t = 4 * g5 + j;
            float Tprev = (t == 0) ? E2 : E2 * Pl[t - 1];
            float w = Tprev - E2 * Pl[t];
            float zk = myz[t];
            float e0 = exp2f(fmaf(fB[0], zk, fA[0]) * NEGL2E);
            float e1 = exp2f(fmaf(fB[1], zk, fA[1]) * NEGL2E);
            float e2 = exp2f(fmaf(fB[2], zk, fA[2]) * NEGL2E);
            a0 = fmaf(w, fast_rcp(1.0f + e0), a0);
            a1 = fmaf(w, fast_rcp(1.0f + e1), a1);
            a2 = fmaf(w, fast_rcp(1.0f + e2), a2);
            ad = fmaf(w, zk, ad);
            wq[j] = w;
        }
        *reinterpret_cast<float4*>(wptr + 4 * g5) =
            make_float4(wq[0], wq[1], wq[2], wq[3]);
    }

    // --- group reduce rgb/depth, lane 0 writes -------------------------------
    a0 += __shfl_xor(a0, 1); a0 += __shfl_xor(a0, 2);
    a1 += __shfl_xor(a1, 1); a1 += __shfl_xor(a1, 2);
    a2 += __shfl_xor(a2, 1); a2 += __shfl_xor(a2, 2);
    ad += __shfl_xor(ad, 1); ad += __shfl_xor(ad, 2);
    if (gl == 0) {
        out[(size_t)ray * 3 + 0] = a0;
        out[(size_t)ray * 3 + 1] = a1;
        out[(size_t)ray * 3 + 2] = a2;
        out[(size_t)nrays * 3 + ray] = ad;
    }
}

extern "C" void kernel_launch(void* const* d_in, const int* in_sizes, int n_in,
                              void* d_out, int out_size, void* d_ws, size_t ws_size,
                              hipStream_t stream) {
    const float* ros = (const float*)d_in[0];
    const float* rds = (const float*)d_in[1];
    const float* w_sigma = (const float*)d_in[2];
    const float* w_feat = (const float*)d_in[3];
    const float* u = (const float*)d_in[4];
    float* out = (float*)d_out;

    int nrays = in_sizes[0] / 3;          // 131072
    int grid = nrays / RPB;               // 4096 blocks of 128 threads
    VolumeRenderer_16192026706363_kernel<<<grid, BLK, 0, stream>>>(
        ros, rds, w_sigma, w_feat, u, out, nrays);
}